// Round 1
// baseline (524.329 us; speedup 1.0000x reference)
//
#include <hip/hip_runtime.h>
#include <hip/hip_bf16.h>

// SectorGCN R8: attack k_gather1/k_gather2 latency serialization.
// - contiguous slices + LDS-staged edata (removes HBM latency from the
//   dependent chain edata->h~ gather->ds_add)
// - 8-deep unrolled tiles, bf16x2 (4B) gathers: 8 lanes/edge, 2x MLP per
//   instruction, register room for 8 outstanding gathers per wave.
// 64-node buckets (NB=1563). N=100000, E=3200000, d_in=128, d_h=16.

#define DH 16
#define BSH 6
#define BNODES 64
#define NB_MAX 1568
#define CHUNK 4096        // scatter chunk
#define HCHUNK 8192       // hist chunk
#define NSLICE 4
#define SE_CAP 768        // staged edges per chunk (gather1)
#define SE2_CAP 1280      // staged edges per chunk (gather2)

__global__ __launch_bounds__(256) void k_Ahist(const int* __restrict__ col,
                                               int* __restrict__ gCnt, int E, int NB) {
    __shared__ int lh[NB_MAX];
    const int tid = threadIdx.x;
    for (int i = tid; i < NB; i += 256) lh[i] = 0;
    __syncthreads();
    const int base = blockIdx.x * HCHUNK;
    #pragma unroll
    for (int k = 0; k < 32; ++k) {
        int e = base + tid + 256 * k;
        if (e < E) atomicAdd(&lh[col[e] >> BSH], 1);
    }
    __syncthreads();
    for (int i = tid; i < NB; i += 256) {
        int v = lh[i];
        if (v) atomicAdd(&gCnt[i], v);
    }
}

// exclusive scan of gCnt[NB], NB <= 2048 (2 elems/thread)
__global__ __launch_bounds__(1024) void k_Ascan(const int* __restrict__ gCnt,
                                                int* __restrict__ gBase,
                                                int* __restrict__ gCursor,
                                                int NB, int E) {
    __shared__ int s[1024];
    const int t = threadIdx.x;
    const int i0 = 2 * t, i1 = 2 * t + 1;
    int a = (i0 < NB) ? gCnt[i0] : 0;
    int b = (i1 < NB) ? gCnt[i1] : 0;
    int v = a + b;
    s[t] = v;
    __syncthreads();
    for (int off = 1; off < 1024; off <<= 1) {
        int u = (t >= off) ? s[t - off] : 0;
        __syncthreads();
        s[t] += u;
        __syncthreads();
    }
    int ex = s[t] - v;
    if (i0 < NB) { gBase[i0] = ex;     gCursor[i0] = ex; }
    if (i1 < NB) { gBase[i1] = ex + a; gCursor[i1] = ex + a; }
    if (t == 0) gBase[NB] = E;
}

// LDS-staged scatter: count -> local scan -> per-(block,bucket) run
// reservation -> place sorted in LDS -> linear (coalesced-run) write-out.
__global__ __launch_bounds__(256) void k_Ascatter(const int* __restrict__ row,
                                                  const int* __restrict__ col,
                                                  const float* __restrict__ ew,
                                                  int* __restrict__ gCursor,
                                                  uint2* __restrict__ edata,
                                                  int E, int NB) {
    __shared__ int lh[NB_MAX];      // counts, then (globalRun - localBase)
    __shared__ int lbase[NB_MAX];
    __shared__ int lcur[NB_MAX];
    __shared__ int tsum[256];
    __shared__ unsigned short sbuck[CHUNK];
    __shared__ uint2 stage[CHUNK];  // 32 KB
    const int tid = threadIdx.x;
    for (int i = tid; i < NB; i += 256) lh[i] = 0;
    __syncthreads();
    const int base = blockIdx.x * CHUNK;
    int r_[16], c_[16];
    float w_[16];
    #pragma unroll
    for (int k = 0; k < 16; ++k) {
        int e = base + tid + 256 * k;
        bool ok = e < E;
        c_[k] = ok ? col[e] : -1;
        r_[k] = ok ? row[e] : 0;
        w_[k] = ok ? ew[e] : 0.f;
        if (ok) atomicAdd(&lh[c_[k] >> BSH], 1);
    }
    __syncthreads();
    const int t0 = tid * 8;
    int c8[8];
    int mysum = 0;
    #pragma unroll
    for (int k = 0; k < 8; ++k) {
        c8[k] = (t0 + k < NB) ? lh[t0 + k] : 0;
        mysum += c8[k];
    }
    tsum[tid] = mysum;
    __syncthreads();
    for (int off = 1; off < 256; off <<= 1) {
        int u = (tid >= off) ? tsum[tid - off] : 0;
        __syncthreads();
        tsum[tid] += u;
        __syncthreads();
    }
    int p = tsum[tid] - mysum;
    #pragma unroll
    for (int k = 0; k < 8; ++k) {
        if (t0 + k < NB) { lbase[t0 + k] = p; lcur[t0 + k] = p; }
        p += c8[k];
    }
    __syncthreads();
    for (int b = tid; b < NB; b += 256) {
        int cnt = lh[b];
        if (cnt) {
            int g = atomicAdd(&gCursor[b], cnt);
            lh[b] = g - lbase[b];
        }
    }
    __syncthreads();
    #pragma unroll
    for (int k = 0; k < 16; ++k) {
        if (c_[k] >= 0) {
            int b = c_[k] >> BSH;
            unsigned rem = (unsigned)(c_[k] & (BNODES - 1));
            int sp = atomicAdd(&lcur[b], 1);
            stage[sp] = make_uint2((unsigned)r_[k] | (rem << 20), __float_as_uint(w_[k]));
            sbuck[sp] = (unsigned short)b;
        }
    }
    __syncthreads();
    int nE = E - base;
    if (nE > CHUNK) nE = CHUNK;
    for (int j = tid; j < nE; j += 256)
        edata[lh[sbuck[j]] + j] = stage[j];
}

// sliced degree: dg[rem] partial in LDS, one global atomic per node per slice
__global__ __launch_bounds__(256) void k_deg(const int* __restrict__ gBase,
                                             const uint2* __restrict__ edata,
                                             float* __restrict__ deg, int N) {
    __shared__ float dg[BNODES];
    const int tid = threadIdx.x;
    if (tid < BNODES) dg[tid] = 0.f;
    __syncthreads();
    const int b = blockIdx.x;
    const int s = gBase[b], e = gBase[b + 1];
    for (int i = s + blockIdx.y * 256 + tid; i < e; i += 512) {
        uint2 ed = edata[i];
        atomicAdd(&dg[ed.x >> 20], __uint_as_float(ed.y));
    }
    __syncthreads();
    int node = (b << BSH) + tid;
    if (tid < BNODES && node < N && dg[tid] != 0.f)
        atomicAdd(&deg[node], dg[tid]);
}

// h~ = rsqrt(deg+1) * (x @ W1) stored as bf16; also stores dinv (fp32).
__global__ __launch_bounds__(256) void k_h1(const float* __restrict__ x,
                                            const float* __restrict__ W1,
                                            const float* __restrict__ deg,
                                            float* __restrict__ dinv,
                                            __hip_bfloat16* __restrict__ hdb) {
    __shared__ float Ws[128 * DH];
    __shared__ float xs[16 * 132];
    const int t = threadIdx.x;
    const int node0 = blockIdx.x * 16;
    #pragma unroll
    for (int i = 0; i < 8; ++i) Ws[t + 256 * i] = W1[t + 256 * i];
    const float4* xg = (const float4*)(x + (size_t)node0 * 128);
    #pragma unroll
    for (int it = 0; it < 2; ++it) {
        int idx = t + 256 * it;
        int n = idx >> 5, k4 = idx & 31;
        float4 v = xg[n * 32 + k4];
        *(float4*)(&xs[n * 132 + k4 * 4]) = v;
    }
    __syncthreads();
    const int node = t >> 4, feat = t & 15;
    const float* xr = &xs[node * 132];
    float acc = 0.f;
    #pragma unroll 8
    for (int k = 0; k < 128; ++k) acc += xr[k] * Ws[k * DH + feat];
    const int v = node0 + node;
    const float di = rsqrtf(deg[v] + 1.0f);
    if (feat == 0) dinv[v] = di;
    hdb[(size_t)v * DH + feat] = __float2bfloat16(di * acc);
}

// layer-1 gather, R8: contiguous slice + LDS-staged edata + unroll-8 tiles.
// 32 groups x 8 lanes; each lane handles a bf16x2 feature pair (4B gather).
// acc[rem][f] += w * h~[r][f]; 64x16 partial strip out per (bucket,slice).
__global__ __launch_bounds__(256) void k_gather1(
    const int* __restrict__ gBase, const uint2* __restrict__ edata,
    const __hip_bfloat16* __restrict__ hdb, float* __restrict__ partial) {
    __shared__ float acc[BNODES][DH + 1];
    __shared__ uint2 se[SE_CAP];
    const int tid = threadIdx.x;
    for (int i = tid; i < BNODES * (DH + 1); i += 256) ((float*)acc)[i] = 0.f;
    const int b = blockIdx.x, sl = blockIdx.y;
    const int s = gBase[b], e = gBase[b + 1];
    const int L = e - s;
    const int per = (L + NSLICE - 1) / NSLICE;
    const int s0 = s + sl * per;
    const int e0 = (s0 + per < e) ? (s0 + per) : e;
    const int g = tid >> 3;        // 0..31: edge slot within tile
    const int f2 = tid & 7;        // feature pair: feats {2*f2, 2*f2+1}
    const uint* __restrict__ hp = (const uint*)hdb;   // node r: hp[r*8 + f2]

    for (int c0 = s0; c0 < e0; c0 += SE_CAP) {
        const int len = ((e0 - c0) < SE_CAP) ? (e0 - c0) : SE_CAP;
        __syncthreads();           // acc-init done / previous se reads done
        for (int j = tid; j < len; j += 256) se[j] = edata[c0 + j];
        __syncthreads();
        const int nfull = len & ~255;
        for (int j0 = 0; j0 < nfull; j0 += 256) {
            uint2 ed[8];
            uint hv[8];
            #pragma unroll
            for (int k = 0; k < 8; ++k) ed[k] = se[j0 + g + k * 32];
            #pragma unroll
            for (int k = 0; k < 8; ++k)
                hv[k] = hp[(size_t)(ed[k].x & 0xFFFFFu) * 8 + f2];
            #pragma unroll
            for (int k = 0; k < 8; ++k) {
                const float w = __uint_as_float(ed[k].y);
                const int rem = ed[k].x >> 20;
                atomicAdd(&acc[rem][2 * f2],
                          w * __uint_as_float(hv[k] << 16));
                atomicAdd(&acc[rem][2 * f2 + 1],
                          w * __uint_as_float(hv[k] & 0xFFFF0000u));
            }
        }
        for (int j = nfull + g; j < len; j += 32) {
            const uint2 ed = se[j];
            const uint hv = hp[(size_t)(ed.x & 0xFFFFFu) * 8 + f2];
            const float w = __uint_as_float(ed.y);
            const int rem = ed.x >> 20;
            atomicAdd(&acc[rem][2 * f2],     w * __uint_as_float(hv << 16));
            atomicAdd(&acc[rem][2 * f2 + 1], w * __uint_as_float(hv & 0xFFFF0000u));
        }
    }
    __syncthreads();
    float* ps = partial + ((size_t)b * NSLICE + sl) * (DH * BNODES);
    for (int i = tid; i < DH * BNODES; i += 256)
        ps[i] = acc[i >> 4][i & 15];
}

// reduce slices + self-loop + bias + relu + dot(W2) -> q (bf16) ; init out
__global__ __launch_bounds__(256) void k_fin1(
    const float* __restrict__ partial, const float* __restrict__ dinv,
    const __hip_bfloat16* __restrict__ hdb, const float* __restrict__ b1,
    const float* __restrict__ W2, const float* __restrict__ b2,
    __hip_bfloat16* __restrict__ qb, float* __restrict__ out, int N) {
    __shared__ float acc[BNODES][DH + 1];
    __shared__ float b1s[DH], W2s[DH];
    const int tid = threadIdx.x;
    if (tid < DH) { b1s[tid] = b1[tid]; W2s[tid] = W2[tid]; }
    const int b = blockIdx.x;
    const float* ps = partial + (size_t)b * NSLICE * (DH * BNODES);
    for (int i = tid; i < DH * BNODES; i += 256) {
        float s = 0.f;
        #pragma unroll
        for (int sl = 0; sl < NSLICE; ++sl) s += ps[sl * (DH * BNODES) + i];
        acc[i >> 4][i & 15] = s;
    }
    __syncthreads();
    int node = (b << BSH) + tid;
    if (tid < BNODES && node < N) {
        float dc = dinv[node];
        const __hip_bfloat16* hs = hdb + (size_t)node * DH;
        float t = 0.f;
        #pragma unroll
        for (int f = 0; f < DH; ++f) {
            float hv = __bfloat162float(hs[f]);
            t += fmaxf(dc * (acc[tid][f] + hv) + b1s[f], 0.f) * W2s[f];
        }
        float qq = dc * t;
        qb[node] = __float2bfloat16(qq);
        out[node] = b2[0] + dc * qq;    // bias + self-loop term of layer 2
    }
}

// layer-2 gather, R8: contiguous half + LDS-staged edata + per-lane edges
// (unroll 4). a2[rem] += w*q[r] (q bf16, L2-resident);
// out[node] += dinv*a2 (1 global atomic per node per half)
__global__ __launch_bounds__(256) void k_gather2(
    const int* __restrict__ gBase, const uint2* __restrict__ edata,
    const float* __restrict__ dinv, const __hip_bfloat16* __restrict__ qb,
    float* __restrict__ out, int N) {
    __shared__ float a2[BNODES];
    __shared__ uint2 se[SE2_CAP];
    const int tid = threadIdx.x;
    if (tid < BNODES) a2[tid] = 0.f;
    const int b = blockIdx.x;
    const int s = gBase[b], e = gBase[b + 1];
    const int L = e - s;
    const int per = (L + 1) >> 1;
    const int s0 = s + blockIdx.y * per;
    const int e0 = (s0 + per < e) ? (s0 + per) : e;
    const ushort* __restrict__ qp = (const ushort*)qb;

    for (int c0 = s0; c0 < e0; c0 += SE2_CAP) {
        const int len = ((e0 - c0) < SE2_CAP) ? (e0 - c0) : SE2_CAP;
        __syncthreads();
        for (int j = tid; j < len; j += 256) se[j] = edata[c0 + j];
        __syncthreads();
        const int nfull = len & ~1023;
        for (int j0 = 0; j0 < nfull; j0 += 1024) {
            uint2 ed[4];
            uint qv[4];
            #pragma unroll
            for (int k = 0; k < 4; ++k) ed[k] = se[j0 + tid + k * 256];
            #pragma unroll
            for (int k = 0; k < 4; ++k)
                qv[k] = (uint)qp[ed[k].x & 0xFFFFFu];
            #pragma unroll
            for (int k = 0; k < 4; ++k)
                atomicAdd(&a2[ed[k].x >> 20],
                          __uint_as_float(ed[k].y) * __uint_as_float(qv[k] << 16));
        }
        for (int j = nfull + tid; j < len; j += 256) {
            const uint2 ed = se[j];
            const float q = __uint_as_float((uint)qp[ed.x & 0xFFFFFu] << 16);
            atomicAdd(&a2[ed.x >> 20], __uint_as_float(ed.y) * q);
        }
    }
    __syncthreads();
    int node = (b << BSH) + tid;
    if (tid < BNODES && node < N && a2[tid] != 0.f)
        atomicAdd(&out[node], dinv[node] * a2[tid]);
}

extern "C" void kernel_launch(void* const* d_in, const int* in_sizes, int n_in,
                              void* d_out, int out_size, void* d_ws, size_t ws_size,
                              hipStream_t stream) {
    const float* x  = (const float*)d_in[0];
    const int*   ei = (const int*)d_in[1];
    const float* ew = (const float*)d_in[2];
    const float* W1 = (const float*)d_in[3];
    const float* b1 = (const float*)d_in[4];
    const float* W2 = (const float*)d_in[5];
    const float* b2 = (const float*)d_in[6];
    float* out = (float*)d_out;

    const int N = in_sizes[0] / 128;       // 100000
    const int E = in_sizes[2];             // 3200000
    const int* row = ei;
    const int* col = ei + E;
    const int NB = (N + BNODES - 1) >> BSH;   // 1563
    const int NBp = (NB + 3) & ~3;

    int* gCnt    = (int*)d_ws;                 // NBp
    float* deg   = (float*)(gCnt + NBp);       // N (memset with gCnt)
    int* gBase   = (int*)(deg + N);            // NBp (uses NB+1)
    int* gCursor = gBase + NBp;                // NBp
    float* dinv  = (float*)(gCursor + NBp);    // N
    __hip_bfloat16* hdb = (__hip_bfloat16*)(dinv + N);   // 16N bf16 = 3.2 MB
    __hip_bfloat16* qb  = hdb + (size_t)16 * N;          // N bf16
    uintptr_t pp = (uintptr_t)(qb + N);
    pp = (pp + 15) & ~(uintptr_t)15;
    float* partial = (float*)pp;               // NB*NSLICE*1024 floats = 25.6 MB
    uintptr_t ep = (uintptr_t)(partial + (size_t)NB * NSLICE * (DH * BNODES));
    ep = (ep + 15) & ~(uintptr_t)15;
    uint2* edata = (uint2*)ep;                 // E

    const int hblocks = (E + HCHUNK - 1) / HCHUNK;  // 391
    const int sblocks = (E + CHUNK - 1) / CHUNK;    // 782

    hipMemsetAsync(gCnt, 0, ((size_t)NBp + N) * sizeof(int), stream);
    k_Ahist<<<hblocks, 256, 0, stream>>>(col, gCnt, E, NB);
    k_Ascan<<<1, 1024, 0, stream>>>(gCnt, gBase, gCursor, NB, E);
    k_Ascatter<<<sblocks, 256, 0, stream>>>(row, col, ew, gCursor, edata, E, NB);
    k_deg<<<dim3(NB, 2), 256, 0, stream>>>(gBase, edata, deg, N);
    k_h1<<<N / 16, 256, 0, stream>>>(x, W1, deg, dinv, hdb);
    k_gather1<<<dim3(NB, NSLICE), 256, 0, stream>>>(gBase, edata, hdb, partial);
    k_fin1<<<NB, 256, 0, stream>>>(partial, dinv, hdb, b1, W2, b2, qb, out, N);
    k_gather2<<<dim3(NB, 2), 256, 0, stream>>>(gBase, edata, dinv, qb, out, N);
}